// Round 7
// baseline (237.586 us; speedup 1.0000x reference)
//
#include <hip/hip_runtime.h>

// RGCN_70566312673746: out[e,o] = xsum[e] * sum_r (1/cs[e,r]) * Wsum[r,o]
//   Wsum[r,o] = sum_i W[r,i,o].  E=100000, R=64, I=256, O=256.
//   edge_index is UNUSED by the reference output.
//
// Round-8 structure (R5 post-mortem: the W-frag hoist worked — VGPR 36->128,
// serialized wsumT chain gone, 91->81us — but OccupancyPercent fell 40->14.6%:
// 2048 waves / 1024 SIMDs = 2 waves/SIMD, so the kernel is now latency-bound
// by WAVE COUNT. Measured quadrants: R4 = many waves x serial chain (91us),
// R5 = few waves x parallel loads (81us). This round: the missing quadrant —
// 6250 waves x parallel loads. At VGPR=128 the RF supports 16 waves/SIMD and
// 17KB LDS/block allows 8 blocks/CU, so nearly the whole 1563-block grid is
// co-resident. HBM bytes are clean (62.7MB fetch + 100MB write = 163MB ->
// 26us floor @ 6.3TB/s):
//   K1 wsum_kernel: verbatim harness-verified Wsum^T bf16 pass (~5us).
//   K2 out_kernel: R5 wave body, ONE tile per wave (no grid-stride loop).
//      - W^T frags hoisted per wave into 128 VGPRs (32 independent L2 loads,
//        one latency, amortized over the tile).
//      - x: 16 coalesced 1KB row loads, 8 in flight; 6-level shfl_xor
//        butterfly row sums; xs = s[lm] by unrolled uniform-select.
//      - cs: 4 coalesced 1KB loads -> per-wave padded LDS scratch (no
//        barrier, same-wave DS ordering) -> verified d0..d3 frag quartet.
//      - MFMA mapping (D[o][e]: o=ot*16+q*4+rg, e=gw*16+lm) and float4
//        stores byte-identical to the harness-verified R3/R4/R5 kernels.
//      __launch_bounds__(256, 4): allow 4+ waves/SIMD residency.

constexpr int En = 100000;
constexpr int Rn = 64;
constexpr int In = 256;
constexpr int On = 256;
constexpr int TILES = En / 16;   // 6250, exact
constexpr int CSP   = 68;        // padded cs row stride in LDS (floats)

typedef short bf16x8 __attribute__((ext_vector_type(8)));
typedef float floatx4 __attribute__((ext_vector_type(4)));

// round-to-nearest-even fp32 -> bf16 bits (finite values only)
static __device__ __forceinline__ short f2bf(float f) {
    unsigned u = __builtin_bit_cast(unsigned, f);
    unsigned r = (u + 0x7FFFu + ((u >> 16) & 1u)) >> 16;
    return (short)r;
}

// ---- K1: Wsum^T[o][r] = bf16(sum_i W[r,i,o]).  block b: r=b>>2, o-quarter
//      h=b&3.  1024 threads: o_local = t&63, i-chunk ic = t>>6 (16 i's). ----
__global__ __launch_bounds__(1024) void wsum_kernel(const float* __restrict__ W,
                                                    short* __restrict__ wsumT) {
    __shared__ float red[16][65];
    const int r  = blockIdx.x >> 2;
    const int h  = blockIdx.x & 3;
    const int ol = threadIdx.x & 63;
    const int ic = threadIdx.x >> 6;
    const int o  = h * 64 + ol;
    const float* base = W + ((size_t)r * In + (size_t)ic * 16) * On + o;
    float s = 0.f;
#pragma unroll
    for (int i = 0; i < 16; ++i) s += base[(size_t)i * On];
    red[ic][ol] = s;
    __syncthreads();
    if (ic == 0) {
        float t = 0.f;
#pragma unroll
        for (int j = 0; j < 16; ++j) t += red[j][ol];
        wsumT[o * Rn + r] = f2bf(t);
    }
}

// ---- K2: W-frag hoist + ONE 16-e-row tile per wave (6252 waves).
//      Lane (q = ln>>4, lm = ln&15): e = gw*16+lm.
//      MFMA computes D[o][e]: o = ot*16 + q*4 + rg. ----
__global__ __launch_bounds__(256, 4) void out_kernel(const float* __restrict__ x,
                                                     const float* __restrict__ cs,
                                                     const short* __restrict__ wsumT,
                                                     float* __restrict__ out) {
    __shared__ float lds_cs[4][16 * CSP];      // per-wave scratch, no sharing
    const int wid = (int)threadIdx.x >> 6;
    const int gw  = (int)blockIdx.x * 4 + wid;
    if (gw >= TILES) return;                   // no barriers: early-exit safe
    const int ln  = (int)threadIdx.x & 63;
    const int lm  = ln & 15;
    const int q   = ln >> 4;

    // ---- hoist W^T fragments for all 16 o-tiles: 32 INDEPENDENT loads,
    //      all issue back-to-back, one L2 latency total.
    //      A[m=o_local=lm][k=r=q*8+j].
    bf16x8 wa0[16], wa1[16];
    const short* wbase = wsumT + lm * Rn + q * 8;
#pragma unroll
    for (int ot = 0; ot < 16; ++ot) {
        const short* p = wbase + ot * 16 * Rn;
        wa0[ot] = *(const bf16x8*)p;          // r = q*8 .. q*8+7
        wa1[ot] = *(const bf16x8*)(p + 32);   // r = 32+q*8 ..
    }

    // ---- cs tile: 16 rows x 256B = 4KB as 4 coalesced 1KB loads.
    const float4* csb = (const float4*)(cs + (size_t)gw * 16 * Rn);
    const float4 cv0 = csb[0 * 64 + ln];
    const float4 cv1 = csb[1 * 64 + ln];
    const float4 cv2 = csb[2 * 64 + ln];
    const float4 cv3 = csb[3 * 64 + ln];

    // ---- x tile: 16 rows x 1KB as 16 coalesced loads, 8 in flight;
    //      full-wave butterfly reduce per row.
    const float4* xb = (const float4*)(x + (size_t)gw * 16 * In);
    float s[16];
#pragma unroll
    for (int j0 = 0; j0 < 16; j0 += 8) {
        float4 v[8];
#pragma unroll
        for (int j = 0; j < 8; ++j) v[j] = xb[(j0 + j) * 64 + ln];
#pragma unroll
        for (int j = 0; j < 8; ++j) {
            float tt = (v[j].x + v[j].y) + (v[j].z + v[j].w);
#pragma unroll
            for (int m = 1; m <= 32; m <<= 1) tt += __shfl_xor(tt, m, 64);
            s[j0 + j] = tt;   // wave-uniform: sum of row j0+j
        }
    }
    float xs = s[0];
#pragma unroll
    for (int j = 1; j < 16; ++j) xs = (lm == j) ? s[j] : xs;  // xs = s[lm]

    // ---- cs -> per-wave LDS (stride 68 breaks bank alignment), then read
    //      back the exact d0..d3 quartet (same-wave DS ordering, no barrier).
    {
        float* lw = &lds_cs[wid][(ln >> 4) * CSP + (ln & 15) * 4];
        *(float4*)(lw + 0 * 4 * CSP) = cv0;
        *(float4*)(lw + 1 * 4 * CSP) = cv1;
        *(float4*)(lw + 2 * 4 * CSP) = cv2;
        *(float4*)(lw + 3 * 4 * CSP) = cv3;
    }
    const float* lr = &lds_cs[wid][lm * CSP + q * 8];
    const float4 d0 = *(const float4*)(lr + 0);    // r = q*8   .. q*8+3
    const float4 d1 = *(const float4*)(lr + 4);    // r = q*8+4 .. q*8+7
    const float4 d2 = *(const float4*)(lr + 32);   // r = 32+q*8 ..
    const float4 d3 = *(const float4*)(lr + 36);

    // ---- B frags: B[k=r=q*8+j][n=e_local=lm] = bf16(1/cs[e][r])
    bf16x8 b0, b1;
    {
        const float rv[16] = {d0.x, d0.y, d0.z, d0.w, d1.x, d1.y, d1.z, d1.w,
                              d2.x, d2.y, d2.z, d2.w, d3.x, d3.y, d3.z, d3.w};
#pragma unroll
        for (int j = 0; j < 8; ++j) {
            b0[j] = f2bf(__builtin_amdgcn_rcpf(rv[j]));
            b1[j] = f2bf(__builtin_amdgcn_rcpf(rv[8 + j]));
        }
    }

    float* orow = out + (size_t)(gw * 16 + lm) * On + q * 4;
#pragma unroll
    for (int ot = 0; ot < 16; ++ot) {
        floatx4 acc = {0.f, 0.f, 0.f, 0.f};
        acc = __builtin_amdgcn_mfma_f32_16x16x32_bf16(wa0[ot], b0, acc, 0, 0, 0);
        acc = __builtin_amdgcn_mfma_f32_16x16x32_bf16(wa1[ot], b1, acc, 0, 0, 0);
        // D: row=q*4+rg -> o, col=lm -> e; 4 consecutive o => float4 store
        const float4 st = make_float4(acc[0] * xs, acc[1] * xs,
                                      acc[2] * xs, acc[3] * xs);
        *(float4*)(orow + ot * 16) = st;
    }
}

extern "C" void kernel_launch(void* const* d_in, const int* in_sizes, int n_in,
                              void* d_out, int out_size, void* d_ws, size_t ws_size,
                              hipStream_t stream) {
    const float* x  = (const float*)d_in[0];   // (E, I) fp32
    const float* cs = (const float*)d_in[1];   // (E, R) fp32
    const float* W  = (const float*)d_in[2];   // (R, I, O) fp32
    // d_in[3] = edge_index: unused by the reference output.
    float* out = (float*)d_out;

    short* wsumT = (short*)d_ws;               // 32 KB bf16 [o][r]

    wsum_kernel<<<dim3(256), dim3(1024), 0, stream>>>(W, wsumT);
    out_kernel<<<dim3((TILES + 3) / 4), dim3(256), 0, stream>>>(
        x, cs, wsumT, out);
}